// Round 12
// baseline (1244.130 us; speedup 1.0000x reference)
//
#include <hip/hip_runtime.h>
#include <math.h>

// Force numpy-style arithmetic: no FMA contraction, no reassociation.
// RF kernels use explicit fmaf() where fusion is wanted (smooth ops).
#pragma clang fp contract(off)
#pragma clang fp reassociate(off)

#define NU 100000
#define NI 50000
#define NT 150000
#define DD 64
#define NE 2000000
#define NTD (NT * DD)
#define NPART 8
#define PARTW_U (NU / NPART)   // 12500 users per partition
#define PARTW_I (NI / NPART)   // 6250 items per partition
#define NCHUNK 256
#define CHW ((NE + NCHUNK - 1) / NCHUNK)   // 7813 edges per chunk

// XCD-partitioned, endpoint-split count: user pass reads eu only.
__global__ __launch_bounds__(256) void count_u_k(const int* __restrict__ eu, int* __restrict__ cnt) {
  int part = blockIdx.x & 7;
  int chunk = blockIdx.x >> 3;
  int lo = part * PARTW_U, hi = lo + PARTW_U;
  int e0 = chunk * CHW;
  int e1 = e0 + CHW; if (e1 > NE) e1 = NE;
  for (int e = e0 + threadIdx.x; e < e1; e += 256) {
    int u = eu[e];
    if (u >= lo && u < hi) atomicAdd(&cnt[u], 1);
  }
}

__global__ __launch_bounds__(256) void count_i_k(const int* __restrict__ ei, int* __restrict__ cnt) {
  int part = blockIdx.x & 7;
  int chunk = blockIdx.x >> 3;
  int lo = part * PARTW_I, hi = lo + PARTW_I;
  int e0 = chunk * CHW;
  int e1 = e0 + CHW; if (e1 > NE) e1 = NE;
  for (int e = e0 + threadIdx.x; e < e1; e += 256) {
    int it = ei[e];
    if (it >= lo && it < hi) atomicAdd(&cnt[NU + it], 1);
  }
}

__global__ __launch_bounds__(1024) void scanA_k(const int* __restrict__ cnt, int* __restrict__ lexcl,
                                                int* __restrict__ partials, int n) {
  int idx = blockIdx.x * 1024 + threadIdx.x;
  int v = (idx < n) ? cnt[idx] : 0;
  int lane = threadIdx.x & 63;
  int wid = threadIdx.x >> 6;
  int x = v;
#pragma unroll
  for (int off = 1; off < 64; off <<= 1) {
    int y = __shfl_up(x, off, 64);
    if (lane >= off) x += y;
  }
  __shared__ int wtot[16], woff[16];
  if (lane == 63) wtot[wid] = x;
  __syncthreads();
  if (threadIdx.x == 0) {
    int a = 0;
#pragma unroll
    for (int w = 0; w < 16; ++w) { woff[w] = a; a += wtot[w]; }
    partials[blockIdx.x] = a;
  }
  __syncthreads();
  if (idx < n) lexcl[idx] = x - v + woff[wid];
}

__global__ __launch_bounds__(64) void scanB_k(int* __restrict__ partials, int* __restrict__ row, int nchunks) {
  int lane = threadIdx.x;
  int carry = 0;
  for (int base = 0; base < nchunks; base += 64) {
    int idx = base + lane;
    int v = (idx < nchunks) ? partials[idx] : 0;
    int x = v;
#pragma unroll
    for (int off = 1; off < 64; off <<= 1) {
      int y = __shfl_up(x, off, 64);
      if (lane >= off) x += y;
    }
    if (idx < nchunks) partials[idx] = carry + x - v;
    carry += __shfl(x, 63, 64);
  }
  if (lane == 0) row[NT] = carry;
}

__global__ __launch_bounds__(1024) void scanC_k(int* __restrict__ row, int* __restrict__ cursor,
                                                float* __restrict__ coef, const int* __restrict__ partials, int n) {
  int idx = blockIdx.x * 1024 + threadIdx.x;
  if (idx >= n) return;
  int c = cursor[idx];  // raw count
  int fin = row[idx] + partials[blockIdx.x];
  row[idx] = fin;
  cursor[idx] = fin;
  coef[idx] = (float)pow((double)(c > 0 ? c : 1), -0.5);
}

// Sliced + XCD-partitioned fill: one LAUNCH per slice (temporal alignment across blocks
// — the r6 in-kernel slicing failed for lack of it). Slice bounds [s0,s1) are relative
// to each partition's base; the active eid window per XCD (~250-500 KB) is L2-resident
// and single-XCD-owned, so scatter lines get fully populated before writeback.
__global__ __launch_bounds__(256) void fill_u_k(const int* __restrict__ eu,
                                                int* __restrict__ cursor, int* __restrict__ eid,
                                                int s0, int s1) {
  int part = blockIdx.x & 7;
  int chunk = blockIdx.x >> 3;
  int lo = part * PARTW_U + s0, hi = part * PARTW_U + s1;
  int e0 = chunk * CHW;
  int e1 = e0 + CHW; if (e1 > NE) e1 = NE;
  for (int e = e0 + threadIdx.x; e < e1; e += 256) {
    int u = eu[e];
    if (u >= lo && u < hi) {
      int p = atomicAdd(&cursor[u], 1);
      eid[p] = e;
    }
  }
}

__global__ __launch_bounds__(256) void fill_i_k(const int* __restrict__ ei,
                                                int* __restrict__ cursor, int* __restrict__ eid,
                                                int s0, int s1) {
  int part = blockIdx.x & 7;
  int chunk = blockIdx.x >> 3;
  int lo = part * PARTW_I + s0, hi = part * PARTW_I + s1;
  int e0 = chunk * CHW;
  int e1 = e0 + CHW; if (e1 > NE) e1 = NE;
  for (int e = e0 + threadIdx.x; e < e1; e += 256) {
    int it = ei[e];
    if (it >= lo && it < hi) {
      int p = atomicAdd(&cursor[NU + it], 1);
      eid[p] = e;
    }
  }
}

// Rank-sort each segment by edge id -> col in exact edge order (deterministic).
__global__ __launch_bounds__(256) void sort_k(const int* __restrict__ row, const int* __restrict__ eid,
                                              const int* __restrict__ eu, const int* __restrict__ ei,
                                              int* __restrict__ col) {
  int wv = (blockIdx.x * blockDim.x + threadIdx.x) >> 6;
  int lane = threadIdx.x & 63;
  if (wv >= NT) return;
  int beg = row[wv], end = row[wv + 1];
  for (int idx = beg + lane; idx < end; idx += 64) {
    int my = eid[idx];
    int r = 0;
    for (int j = beg; j < end; ++j) r += (eid[j] < my);
    col[beg + r] = (wv < NU) ? (NU + ei[my]) : eu[my];
  }
}

// GCN layer: 4 nodes/wave, 16 lanes x float4 dims, depth-6+6 chunked gather pipeline
// (12 row-loads in flight per node group). Arithmetic bit-identical: per-dim strict
// edge-order sum, separate mul/add rounding; noise pairwise-sum + fixed tree.
// FIRST=1: gather straight from ue/ie + init acc. LAST=1: fused layer mean.
template <int FIRST, int LAST>
__global__ __launch_bounds__(256) void gcn4_k(const float* __restrict__ in, float* __restrict__ out,
                                              float* __restrict__ acc,
                                              const int* __restrict__ row, const int* __restrict__ col,
                                              const float* __restrict__ coef, const float* __restrict__ nz_l,
                                              const float* __restrict__ ue, const float* __restrict__ ie) {
  int wave = (blockIdx.x * blockDim.x + threadIdx.x) >> 6;
  int lane = threadIdx.x & 63;
  int g = lane >> 4, q = lane & 15;
  int node = wave * 4 + g;
  if (node >= NT) return;
  int beg = row[node], end = row[node + 1];
  float cn = coef[node];
  float sx = 0.f, sy = 0.f, sz = 0.f, sw = 0.f;

  const float* gbase;
  if (FIRST) {
    gbase = (node < NU) ? (ie - (size_t)NU * DD) : ue;  // user->item rows, item->user rows
  } else {
    gbase = in;
  }

#define GLD(dv, dc, kk) { int m_ = col[kk]; dc = coef[m_]; dv = *(const float4*)(gbase + (size_t)m_ * DD + q * 4); }
#define GACC(v, c)                                                            \
  {                                                                           \
    float w = cn * c;                                                         \
    sx = sx + (v.x * w); sy = sy + (v.y * w);                                 \
    sz = sz + (v.z * w); sw = sw + (v.w * w);                                 \
  }
  float4 cv0, cv1, cv2, cv3, cv4, cv5;
  float cc0, cc1, cc2, cc3, cc4, cc5;
  int rem = end - beg;
  int k6end = end - (rem % 6);
  int k = beg;
  if (k < k6end) {
    GLD(cv0, cc0, k) GLD(cv1, cc1, k + 1) GLD(cv2, cc2, k + 2)
    GLD(cv3, cc3, k + 3) GLD(cv4, cc4, k + 4) GLD(cv5, cc5, k + 5)
  }
  for (; k < k6end; k += 6) {
    float4 nv0, nv1, nv2, nv3, nv4, nv5;
    float nc0, nc1, nc2, nc3, nc4, nc5;
    bool more = (k + 6) < k6end;
    if (more) {
      GLD(nv0, nc0, k + 6) GLD(nv1, nc1, k + 7) GLD(nv2, nc2, k + 8)
      GLD(nv3, nc3, k + 9) GLD(nv4, nc4, k + 10) GLD(nv5, nc5, k + 11)
    }
    GACC(cv0, cc0) GACC(cv1, cc1) GACC(cv2, cc2)
    GACC(cv3, cc3) GACC(cv4, cc4) GACC(cv5, cc5)
    if (more) {
      cv0 = nv0; cc0 = nc0; cv1 = nv1; cc1 = nc1; cv2 = nv2; cc2 = nc2;
      cv3 = nv3; cc3 = nc3; cv4 = nv4; cc4 = nc4; cv5 = nv5; cc5 = nc5;
    }
  }
  for (; k < end; ++k) {  // tail <= 5
    float4 v; float c;
    GLD(v, c, k)
    GACC(v, c)
  }
#undef GACC
#undef GLD

  // Noise norm, bit-identical: r[j] = sum over k of sq[8k+j] (sequential), tree combine.
  float4 nzv = *(const float4*)(nz_l + (size_t)node * DD + q * 4);
  float4 sq;
  sq.x = nzv.x * nzv.x; sq.y = nzv.y * nzv.y;
  sq.z = nzv.z * nzv.z; sq.w = nzv.w * nzv.w;
  float rA0 = 0.f, rA1 = 0.f, rA2 = 0.f, rA3 = 0.f;
  float rB0 = 0.f, rB1 = 0.f, rB2 = 0.f, rB3 = 0.f;
  int base = g * 16;
#pragma unroll
  for (int kk = 0; kk < 8; ++kk) {
    int le = base + 2 * kk, lo = le + 1;
    rA0 = rA0 + __shfl(sq.x, le, 64);
    rA1 = rA1 + __shfl(sq.y, le, 64);
    rA2 = rA2 + __shfl(sq.z, le, 64);
    rA3 = rA3 + __shfl(sq.w, le, 64);
    rB0 = rB0 + __shfl(sq.x, lo, 64);
    rB1 = rB1 + __shfl(sq.y, lo, 64);
    rB2 = rB2 + __shfl(sq.z, lo, 64);
    rB3 = rB3 + __shfl(sq.w, lo, 64);
  }
  float t01 = rA0 + rA1, t23 = rA2 + rA3;
  float t45 = rB0 + rB1, t67 = rB2 + rB3;
  float tot = (t01 + t23) + (t45 + t67);
  float nrm = __fsqrt_rn(tot);
  float den = fmaxf(nrm, 1e-12f);
  float4 o;
  {
    float nn = nzv.x / den;
    float sg = (sx > 0.f) ? 1.f : ((sx < 0.f) ? -1.f : 0.f);
    o.x = sx + ((sg * nn) * 0.2f);
  }
  {
    float nn = nzv.y / den;
    float sg = (sy > 0.f) ? 1.f : ((sy < 0.f) ? -1.f : 0.f);
    o.y = sy + ((sg * nn) * 0.2f);
  }
  {
    float nn = nzv.z / den;
    float sg = (sz > 0.f) ? 1.f : ((sz < 0.f) ? -1.f : 0.f);
    o.z = sz + ((sg * nn) * 0.2f);
  }
  {
    float nn = nzv.w / den;
    float sg = (sw > 0.f) ? 1.f : ((sw < 0.f) ? -1.f : 0.f);
    o.w = sw + ((sg * nn) * 0.2f);
  }
  size_t boff = (size_t)node * DD + q * 4;
  if (FIRST) {
    const float* ownp = (node < NU) ? (ue + (size_t)node * DD) : (ie + (size_t)(node - NU) * DD);
    float4 own = *(const float4*)(ownp + q * 4);
    *(float4*)(out + boff) = o;
    float4 a;
    a.x = own.x + o.x; a.y = own.y + o.y; a.z = own.z + o.z; a.w = own.w + o.w;
    *(float4*)(acc + boff) = a;
  } else {
    float4 a = *(const float4*)(acc + boff);
    if (LAST) {
      float4 mo;
      mo.x = (a.x + o.x) * 0.25f;
      mo.y = (a.y + o.y) * 0.25f;
      mo.z = (a.z + o.z) * 0.25f;
      mo.w = (a.w + o.w) * 0.25f;
      *(float4*)(out + boff) = mo;
    } else {
      *(float4*)(out + boff) = o;
      a.x = a.x + o.x; a.y = a.y + o.y; a.z = a.z + o.z; a.w = a.w + o.w;
      *(float4*)(acc + boff) = a;
    }
  }
}

// Fused Rankformer layer: ONE gather pass per node (max-free softmax, r9-validated).
// Depth-4 pipeline kept as the ILP-experiment control.
__global__ __launch_bounds__(256) void rfaccum_k(const float* __restrict__ in, float* __restrict__ out,
                                                 const int* __restrict__ row, const int* __restrict__ col) {
  int wave = (blockIdx.x * blockDim.x + threadIdx.x) >> 6;
  int lane = threadIdx.x & 63;
  int g = lane >> 4, q = lane & 15;
  int node = wave * 4 + g;
  if (node >= NT) return;
  int beg = row[node], end = row[node + 1];
  size_t boff = (size_t)node * DD + q * 4;
  float4 e = *(const float4*)(in + boff);
  float rx = 0.f, ry = 0.f, rz = 0.f, rw = 0.f, zacc = 0.f;

#define VLD(dv, kk) { dv = *(const float4*)(in + (size_t)col[kk] * DD + q * 4); }
#define STEP(v)                                                              \
  {                                                                          \
    float d = fmaf(e.x, v.x, fmaf(e.y, v.y, fmaf(e.z, v.z, e.w * v.w)));     \
    d += __shfl_xor(d, 1, 64); d += __shfl_xor(d, 2, 64);                    \
    d += __shfl_xor(d, 4, 64); d += __shfl_xor(d, 8, 64);                    \
    float p = __expf(d);                                                     \
    rx = fmaf(p, v.x, rx); ry = fmaf(p, v.y, ry);                            \
    rz = fmaf(p, v.z, rz); rw = fmaf(p, v.w, rw);                            \
    zacc = zacc + p;                                                         \
  }

  float4 cv0, cv1, cv2, cv3;
  int rem = end - beg;
  int k4end = end - (rem & 3);
  int k = beg;
  if (k < k4end) {
    VLD(cv0, k) VLD(cv1, k + 1) VLD(cv2, k + 2) VLD(cv3, k + 3)
  }
  for (; k < k4end; k += 4) {
    float4 nv0, nv1, nv2, nv3;
    bool more = (k + 4) < k4end;
    if (more) {
      VLD(nv0, k + 4) VLD(nv1, k + 5) VLD(nv2, k + 6) VLD(nv3, k + 7)
    }
    STEP(cv0) STEP(cv1) STEP(cv2) STEP(cv3)
    if (more) { cv0 = nv0; cv1 = nv1; cv2 = nv2; cv3 = nv3; }
  }
  for (; k < end; ++k) {
    float4 v;
    VLD(v, k)
    STEP(v)
  }
#undef STEP
#undef VLD

  float zi = 1.f / fmaxf(zacc, 1e-9f);
  float4 o;
  o.x = 0.5f * e.x + 0.5f * (rx * zi);
  o.y = 0.5f * e.y + 0.5f * (ry * zi);
  o.z = 0.5f * e.z + 0.5f * (rz * zi);
  o.w = 0.5f * e.w + 0.5f * (rw * zi);
  *(float4*)(out + boff) = o;
}

extern "C" void kernel_launch(void* const* d_in, const int* in_sizes, int n_in,
                              void* d_out, int out_size, void* d_ws, size_t ws_size,
                              hipStream_t stream) {
  const float* user_emb = (const float*)d_in[0];
  const float* item_emb = (const float*)d_in[1];
  const float* noise    = (const float*)d_in[2];
  const int*   edge_u   = (const int*)d_in[3];
  const int*   edge_i   = (const int*)d_in[4];
  float* out = (float*)d_out;

  // ws layout (~110 MB)
  float* embA = (float*)d_ws;                      // NTD
  float* embB = embA + (size_t)NTD;                // NTD
  float* coef = embB + (size_t)NTD;                // NT+16
  int*   row  = (int*)(coef + (NT + 16));          // NT+16
  int*   cursor = row + (NT + 16);                 // NT+16
  int*   partials = cursor + (NT + 16);            // 256
  int*   eidt = partials + 256;                    // 2E
  int*   col  = eidt + 2 * (size_t)NE;             // 2E

  float* acc = out;  // layer-mean accumulator lives in d_out until the final RF pass

  const int nchunks = (NT + 1023) / 1024;

  hipMemsetAsync(cursor, 0, (size_t)NT * sizeof(int), stream);
  count_u_k<<<NCHUNK * NPART, 256, 0, stream>>>(edge_u, cursor);
  count_i_k<<<NCHUNK * NPART, 256, 0, stream>>>(edge_i, cursor);
  scanA_k<<<nchunks, 1024, 0, stream>>>(cursor, row, partials, NT);
  scanB_k<<<1, 64, 0, stream>>>(partials, row, nchunks);
  scanC_k<<<nchunks, 1024, 0, stream>>>(row, cursor, coef, partials, NT);
  // Sliced fills: one launch per slice for temporal L2 alignment.
  for (int s = 0; s < 4; ++s)
    fill_u_k<<<NCHUNK * NPART, 256, 0, stream>>>(edge_u, cursor, eidt,
                                                 s * (PARTW_U / 4), (s + 1) * (PARTW_U / 4));
  for (int s = 0; s < 2; ++s)
    fill_i_k<<<NCHUNK * NPART, 256, 0, stream>>>(edge_i, cursor, eidt,
                                                 s * (PARTW_I / 2), (s + 1) * (PARTW_I / 2));

  const int gwave = (NT * 64 + 255) / 256;   // 64-lane-per-node grid (sort)
  const int g4    = (NT / 4 * 64) / 256;     // 4-node-per-wave grids = 9375

  sort_k<<<gwave, 256, 0, stream>>>(row, eidt, edge_u, edge_i, col);

  // L0 (FIRST, gathers from ue/ie, inits acc): -> embB
  gcn4_k<1, 0><<<g4, 256, 0, stream>>>(nullptr, embB, acc, row, col, coef,
                                       noise + 0 * (size_t)NTD, user_emb, item_emb);
  // L1: embB -> embA
  gcn4_k<0, 0><<<g4, 256, 0, stream>>>(embB, embA, acc, row, col, coef,
                                       noise + 1 * (size_t)NTD, user_emb, item_emb);
  // L2 (LAST, fused mean): embA -> embB
  gcn4_k<0, 1><<<g4, 256, 0, stream>>>(embA, embB, acc, row, col, coef,
                                       noise + 2 * (size_t)NTD, user_emb, item_emb);

  // Fused RF layers: embB -> embA -> out
  rfaccum_k<<<g4, 256, 0, stream>>>(embB, embA, row, col);
  rfaccum_k<<<g4, 256, 0, stream>>>(embA, out, row, col);
}

// Round 13
// 1090.207 us; speedup vs baseline: 1.1412x; 1.1412x over previous
//
#include <hip/hip_runtime.h>
#include <math.h>

// Force numpy-style arithmetic: no FMA contraction, no reassociation.
// RF kernels use explicit fmaf() where fusion is wanted (smooth ops).
#pragma clang fp contract(off)
#pragma clang fp reassociate(off)

#define NU 100000
#define NI 50000
#define NT 150000
#define DD 64
#define NE 2000000
#define NTD (NT * DD)
#define NPART 8
#define PARTW_U (NU / NPART)   // 12500 users per partition
#define PARTW_I (NI / NPART)   // 6250 items per partition
#define NCHUNK 256
#define CHW ((NE + NCHUNK - 1) / NCHUNK)   // 7813 edges per chunk

typedef _Float16 half4 __attribute__((ext_vector_type(4)));

// XCD-partitioned, endpoint-split count: user pass reads eu only.
__global__ __launch_bounds__(256) void count_u_k(const int* __restrict__ eu, int* __restrict__ cnt) {
  int part = blockIdx.x & 7;
  int chunk = blockIdx.x >> 3;
  int lo = part * PARTW_U, hi = lo + PARTW_U;
  int e0 = chunk * CHW;
  int e1 = e0 + CHW; if (e1 > NE) e1 = NE;
  for (int e = e0 + threadIdx.x; e < e1; e += 256) {
    int u = eu[e];
    if (u >= lo && u < hi) atomicAdd(&cnt[u], 1);
  }
}

__global__ __launch_bounds__(256) void count_i_k(const int* __restrict__ ei, int* __restrict__ cnt) {
  int part = blockIdx.x & 7;
  int chunk = blockIdx.x >> 3;
  int lo = part * PARTW_I, hi = lo + PARTW_I;
  int e0 = chunk * CHW;
  int e1 = e0 + CHW; if (e1 > NE) e1 = NE;
  for (int e = e0 + threadIdx.x; e < e1; e += 256) {
    int it = ei[e];
    if (it >= lo && it < hi) atomicAdd(&cnt[NU + it], 1);
  }
}

__global__ __launch_bounds__(1024) void scanA_k(const int* __restrict__ cnt, int* __restrict__ lexcl,
                                                int* __restrict__ partials, int n) {
  int idx = blockIdx.x * 1024 + threadIdx.x;
  int v = (idx < n) ? cnt[idx] : 0;
  int lane = threadIdx.x & 63;
  int wid = threadIdx.x >> 6;
  int x = v;
#pragma unroll
  for (int off = 1; off < 64; off <<= 1) {
    int y = __shfl_up(x, off, 64);
    if (lane >= off) x += y;
  }
  __shared__ int wtot[16], woff[16];
  if (lane == 63) wtot[wid] = x;
  __syncthreads();
  if (threadIdx.x == 0) {
    int a = 0;
#pragma unroll
    for (int w = 0; w < 16; ++w) { woff[w] = a; a += wtot[w]; }
    partials[blockIdx.x] = a;
  }
  __syncthreads();
  if (idx < n) lexcl[idx] = x - v + woff[wid];
}

__global__ __launch_bounds__(64) void scanB_k(int* __restrict__ partials, int* __restrict__ row, int nchunks) {
  int lane = threadIdx.x;
  int carry = 0;
  for (int base = 0; base < nchunks; base += 64) {
    int idx = base + lane;
    int v = (idx < nchunks) ? partials[idx] : 0;
    int x = v;
#pragma unroll
    for (int off = 1; off < 64; off <<= 1) {
      int y = __shfl_up(x, off, 64);
      if (lane >= off) x += y;
    }
    if (idx < nchunks) partials[idx] = carry + x - v;
    carry += __shfl(x, 63, 64);
  }
  if (lane == 0) row[NT] = carry;
}

__global__ __launch_bounds__(1024) void scanC_k(int* __restrict__ row, int* __restrict__ cursor,
                                                float* __restrict__ coef, const int* __restrict__ partials, int n) {
  int idx = blockIdx.x * 1024 + threadIdx.x;
  if (idx >= n) return;
  int c = cursor[idx];  // raw count
  int fin = row[idx] + partials[blockIdx.x];
  row[idx] = fin;
  cursor[idx] = fin;
  coef[idx] = (float)pow((double)(c > 0 ? c : 1), -0.5);
}

// XCD-partitioned, endpoint-split fill (r11 form — single launch each; slicing measured -67us).
__global__ __launch_bounds__(256) void fill_u_k(const int* __restrict__ eu,
                                                int* __restrict__ cursor, int* __restrict__ eid) {
  int part = blockIdx.x & 7;
  int chunk = blockIdx.x >> 3;
  int lo = part * PARTW_U, hi = lo + PARTW_U;
  int e0 = chunk * CHW;
  int e1 = e0 + CHW; if (e1 > NE) e1 = NE;
  for (int e = e0 + threadIdx.x; e < e1; e += 256) {
    int u = eu[e];
    if (u >= lo && u < hi) {
      int p = atomicAdd(&cursor[u], 1);
      eid[p] = e;
    }
  }
}

__global__ __launch_bounds__(256) void fill_i_k(const int* __restrict__ ei,
                                                int* __restrict__ cursor, int* __restrict__ eid) {
  int part = blockIdx.x & 7;
  int chunk = blockIdx.x >> 3;
  int lo = part * PARTW_I, hi = lo + PARTW_I;
  int e0 = chunk * CHW;
  int e1 = e0 + CHW; if (e1 > NE) e1 = NE;
  for (int e = e0 + threadIdx.x; e < e1; e += 256) {
    int it = ei[e];
    if (it >= lo && it < hi) {
      int p = atomicAdd(&cursor[NU + it], 1);
      eid[p] = e;
    }
  }
}

// Rank-sort each segment by edge id -> col in exact edge order (deterministic).
__global__ __launch_bounds__(256) void sort_k(const int* __restrict__ row, const int* __restrict__ eid,
                                              const int* __restrict__ eu, const int* __restrict__ ei,
                                              int* __restrict__ col) {
  int wv = (blockIdx.x * blockDim.x + threadIdx.x) >> 6;
  int lane = threadIdx.x & 63;
  if (wv >= NT) return;
  int beg = row[wv], end = row[wv + 1];
  for (int idx = beg + lane; idx < end; idx += 64) {
    int my = eid[idx];
    int r = 0;
    for (int j = beg; j < end; ++j) r += (eid[j] < my);
    col[beg + r] = (wv < NU) ? (NU + ei[my]) : eu[my];
  }
}

// GCN layer: 4 nodes/wave, 16 lanes x float4 dims, depth-4+4 chunked gather pipeline
// (depth-6 measured neutral -> fetch-bound; keep 4). Arithmetic bit-identical: per-dim
// strict edge-order sum, separate mul/add rounding; noise pairwise-sum + fixed tree.
// FIRST=1: gather straight from ue/ie + init acc. LAST=1: fused layer mean -> out (f32)
// AND h16out (fp16 copy for the RF neighbor gathers).
template <int FIRST, int LAST>
__global__ __launch_bounds__(256) void gcn4_k(const float* __restrict__ in, float* __restrict__ out,
                                              float* __restrict__ acc,
                                              const int* __restrict__ row, const int* __restrict__ col,
                                              const float* __restrict__ coef, const float* __restrict__ nz_l,
                                              const float* __restrict__ ue, const float* __restrict__ ie,
                                              _Float16* __restrict__ h16out) {
  int wave = (blockIdx.x * blockDim.x + threadIdx.x) >> 6;
  int lane = threadIdx.x & 63;
  int g = lane >> 4, q = lane & 15;
  int node = wave * 4 + g;
  if (node >= NT) return;
  int beg = row[node], end = row[node + 1];
  float cn = coef[node];
  float sx = 0.f, sy = 0.f, sz = 0.f, sw = 0.f;

  const float* gbase;
  if (FIRST) {
    gbase = (node < NU) ? (ie - (size_t)NU * DD) : ue;  // user->item rows, item->user rows
  } else {
    gbase = in;
  }

#define GLD(dv, dc, kk) { int m_ = col[kk]; dc = coef[m_]; dv = *(const float4*)(gbase + (size_t)m_ * DD + q * 4); }
  float4 cv0, cv1, cv2, cv3;
  float cc0, cc1, cc2, cc3;
  int rem = end - beg;
  int k4end = end - (rem & 3);
  int k = beg;
  if (k < k4end) {
    GLD(cv0, cc0, k) GLD(cv1, cc1, k + 1) GLD(cv2, cc2, k + 2) GLD(cv3, cc3, k + 3)
  }
  for (; k < k4end; k += 4) {
    float4 nv0, nv1, nv2, nv3;
    float nc0, nc1, nc2, nc3;
    bool more = (k + 4) < k4end;
    if (more) {
      GLD(nv0, nc0, k + 4) GLD(nv1, nc1, k + 5) GLD(nv2, nc2, k + 6) GLD(nv3, nc3, k + 7)
    }
    {
      float w = cn * cc0;
      sx = sx + (cv0.x * w); sy = sy + (cv0.y * w); sz = sz + (cv0.z * w); sw = sw + (cv0.w * w);
    }
    {
      float w = cn * cc1;
      sx = sx + (cv1.x * w); sy = sy + (cv1.y * w); sz = sz + (cv1.z * w); sw = sw + (cv1.w * w);
    }
    {
      float w = cn * cc2;
      sx = sx + (cv2.x * w); sy = sy + (cv2.y * w); sz = sz + (cv2.z * w); sw = sw + (cv2.w * w);
    }
    {
      float w = cn * cc3;
      sx = sx + (cv3.x * w); sy = sy + (cv3.y * w); sz = sz + (cv3.z * w); sw = sw + (cv3.w * w);
    }
    if (more) {
      cv0 = nv0; cc0 = nc0; cv1 = nv1; cc1 = nc1;
      cv2 = nv2; cc2 = nc2; cv3 = nv3; cc3 = nc3;
    }
  }
  for (; k < end; ++k) {  // tail <= 3
    float4 v; float c;
    GLD(v, c, k)
    float w = cn * c;
    sx = sx + (v.x * w); sy = sy + (v.y * w); sz = sz + (v.z * w); sw = sw + (v.w * w);
  }
#undef GLD

  // Noise norm, bit-identical: r[j] = sum over k of sq[8k+j] (sequential), tree combine.
  float4 nzv = *(const float4*)(nz_l + (size_t)node * DD + q * 4);
  float4 sq;
  sq.x = nzv.x * nzv.x; sq.y = nzv.y * nzv.y;
  sq.z = nzv.z * nzv.z; sq.w = nzv.w * nzv.w;
  float rA0 = 0.f, rA1 = 0.f, rA2 = 0.f, rA3 = 0.f;
  float rB0 = 0.f, rB1 = 0.f, rB2 = 0.f, rB3 = 0.f;
  int base = g * 16;
#pragma unroll
  for (int kk = 0; kk < 8; ++kk) {
    int le = base + 2 * kk, lo = le + 1;
    rA0 = rA0 + __shfl(sq.x, le, 64);
    rA1 = rA1 + __shfl(sq.y, le, 64);
    rA2 = rA2 + __shfl(sq.z, le, 64);
    rA3 = rA3 + __shfl(sq.w, le, 64);
    rB0 = rB0 + __shfl(sq.x, lo, 64);
    rB1 = rB1 + __shfl(sq.y, lo, 64);
    rB2 = rB2 + __shfl(sq.z, lo, 64);
    rB3 = rB3 + __shfl(sq.w, lo, 64);
  }
  float t01 = rA0 + rA1, t23 = rA2 + rA3;
  float t45 = rB0 + rB1, t67 = rB2 + rB3;
  float tot = (t01 + t23) + (t45 + t67);
  float nrm = __fsqrt_rn(tot);
  float den = fmaxf(nrm, 1e-12f);
  float4 o;
  {
    float nn = nzv.x / den;
    float sg = (sx > 0.f) ? 1.f : ((sx < 0.f) ? -1.f : 0.f);
    o.x = sx + ((sg * nn) * 0.2f);
  }
  {
    float nn = nzv.y / den;
    float sg = (sy > 0.f) ? 1.f : ((sy < 0.f) ? -1.f : 0.f);
    o.y = sy + ((sg * nn) * 0.2f);
  }
  {
    float nn = nzv.z / den;
    float sg = (sz > 0.f) ? 1.f : ((sz < 0.f) ? -1.f : 0.f);
    o.z = sz + ((sg * nn) * 0.2f);
  }
  {
    float nn = nzv.w / den;
    float sg = (sw > 0.f) ? 1.f : ((sw < 0.f) ? -1.f : 0.f);
    o.w = sw + ((sg * nn) * 0.2f);
  }
  size_t boff = (size_t)node * DD + q * 4;
  if (FIRST) {
    const float* ownp = (node < NU) ? (ue + (size_t)node * DD) : (ie + (size_t)(node - NU) * DD);
    float4 own = *(const float4*)(ownp + q * 4);
    *(float4*)(out + boff) = o;
    float4 a;
    a.x = own.x + o.x; a.y = own.y + o.y; a.z = own.z + o.z; a.w = own.w + o.w;
    *(float4*)(acc + boff) = a;
  } else {
    float4 a = *(const float4*)(acc + boff);
    if (LAST) {
      float4 mo;
      mo.x = (a.x + o.x) * 0.25f;
      mo.y = (a.y + o.y) * 0.25f;
      mo.z = (a.z + o.z) * 0.25f;
      mo.w = (a.w + o.w) * 0.25f;
      *(float4*)(out + boff) = mo;
      half4 hh;
      hh.x = (_Float16)mo.x; hh.y = (_Float16)mo.y;
      hh.z = (_Float16)mo.z; hh.w = (_Float16)mo.w;
      *(half4*)(h16out + boff) = hh;
    } else {
      *(float4*)(out + boff) = o;
      a.x = a.x + o.x; a.y = a.y + o.y; a.z = a.z + o.z; a.w = a.w + o.w;
      *(float4*)(acc + boff) = a;
    }
  }
}

// Fused Rankformer layer, fp16 neighbor gather (RF is smooth; |err| budget ~2.5e-4/layer).
// Own row e and all accumulation stay f32. WRITEH=1 also emits the fp16 copy for the
// next RF layer's gather.
template <int WRITEH>
__global__ __launch_bounds__(256) void rfaccum_k(const float* __restrict__ inF,
                                                 const _Float16* __restrict__ inH,
                                                 float* __restrict__ outF,
                                                 _Float16* __restrict__ outH,
                                                 const int* __restrict__ row, const int* __restrict__ col) {
  int wave = (blockIdx.x * blockDim.x + threadIdx.x) >> 6;
  int lane = threadIdx.x & 63;
  int g = lane >> 4, q = lane & 15;
  int node = wave * 4 + g;
  if (node >= NT) return;
  int beg = row[node], end = row[node + 1];
  size_t boff = (size_t)node * DD + q * 4;
  float4 e = *(const float4*)(inF + boff);
  float rx = 0.f, ry = 0.f, rz = 0.f, rw = 0.f, zacc = 0.f;

#define VLD(dv, kk) { dv = *(const half4*)(inH + (size_t)col[kk] * DD + q * 4); }
#define STEP(hv)                                                             \
  {                                                                          \
    float vx = (float)hv.x, vy = (float)hv.y, vz = (float)hv.z, vw = (float)hv.w; \
    float d = fmaf(e.x, vx, fmaf(e.y, vy, fmaf(e.z, vz, e.w * vw)));         \
    d += __shfl_xor(d, 1, 64); d += __shfl_xor(d, 2, 64);                    \
    d += __shfl_xor(d, 4, 64); d += __shfl_xor(d, 8, 64);                    \
    float p = __expf(d);                                                     \
    rx = fmaf(p, vx, rx); ry = fmaf(p, vy, ry);                              \
    rz = fmaf(p, vz, rz); rw = fmaf(p, vw, rw);                              \
    zacc = zacc + p;                                                         \
  }

  half4 cv0, cv1, cv2, cv3;
  int rem = end - beg;
  int k4end = end - (rem & 3);
  int k = beg;
  if (k < k4end) {
    VLD(cv0, k) VLD(cv1, k + 1) VLD(cv2, k + 2) VLD(cv3, k + 3)
  }
  for (; k < k4end; k += 4) {
    half4 nv0, nv1, nv2, nv3;
    bool more = (k + 4) < k4end;
    if (more) {
      VLD(nv0, k + 4) VLD(nv1, k + 5) VLD(nv2, k + 6) VLD(nv3, k + 7)
    }
    STEP(cv0) STEP(cv1) STEP(cv2) STEP(cv3)
    if (more) { cv0 = nv0; cv1 = nv1; cv2 = nv2; cv3 = nv3; }
  }
  for (; k < end; ++k) {
    half4 v;
    VLD(v, k)
    STEP(v)
  }
#undef STEP
#undef VLD

  float zi = 1.f / fmaxf(zacc, 1e-9f);
  float4 o;
  o.x = 0.5f * e.x + 0.5f * (rx * zi);
  o.y = 0.5f * e.y + 0.5f * (ry * zi);
  o.z = 0.5f * e.z + 0.5f * (rz * zi);
  o.w = 0.5f * e.w + 0.5f * (rw * zi);
  *(float4*)(outF + boff) = o;
  if (WRITEH) {
    half4 hh;
    hh.x = (_Float16)o.x; hh.y = (_Float16)o.y;
    hh.z = (_Float16)o.z; hh.w = (_Float16)o.w;
    *(half4*)(outH + boff) = hh;
  }
}

extern "C" void kernel_launch(void* const* d_in, const int* in_sizes, int n_in,
                              void* d_out, int out_size, void* d_ws, size_t ws_size,
                              hipStream_t stream) {
  const float* user_emb = (const float*)d_in[0];
  const float* item_emb = (const float*)d_in[1];
  const float* noise    = (const float*)d_in[2];
  const int*   edge_u   = (const int*)d_in[3];
  const int*   edge_i   = (const int*)d_in[4];
  float* out = (float*)d_out;

  // ws layout (~148 MB)
  float* embA = (float*)d_ws;                      // NTD f32
  float* embB = embA + (size_t)NTD;                // NTD f32
  float* coef = embB + (size_t)NTD;                // NT+16
  int*   row  = (int*)(coef + (NT + 16));          // NT+16
  int*   cursor = row + (NT + 16);                 // NT+16
  int*   partials = cursor + (NT + 16);            // 256
  int*   eidt = partials + 256;                    // 2E
  int*   col  = eidt + 2 * (size_t)NE;             // 2E
  _Float16* H0 = (_Float16*)(col + 2 * (size_t)NE); // NTD fp16
  _Float16* H1 = H0 + (size_t)NTD;                  // NTD fp16

  float* acc = out;  // layer-mean accumulator lives in d_out until the final RF pass

  const int nchunks = (NT + 1023) / 1024;

  hipMemsetAsync(cursor, 0, (size_t)NT * sizeof(int), stream);
  count_u_k<<<NCHUNK * NPART, 256, 0, stream>>>(edge_u, cursor);
  count_i_k<<<NCHUNK * NPART, 256, 0, stream>>>(edge_i, cursor);
  scanA_k<<<nchunks, 1024, 0, stream>>>(cursor, row, partials, NT);
  scanB_k<<<1, 64, 0, stream>>>(partials, row, nchunks);
  scanC_k<<<nchunks, 1024, 0, stream>>>(row, cursor, coef, partials, NT);
  fill_u_k<<<NCHUNK * NPART, 256, 0, stream>>>(edge_u, cursor, eidt);
  fill_i_k<<<NCHUNK * NPART, 256, 0, stream>>>(edge_i, cursor, eidt);

  const int gwave = (NT * 64 + 255) / 256;   // 64-lane-per-node grid (sort)
  const int g4    = (NT / 4 * 64) / 256;     // 4-node-per-wave grids = 9375

  sort_k<<<gwave, 256, 0, stream>>>(row, eidt, edge_u, edge_i, col);

  // L0 (FIRST, gathers from ue/ie, inits acc): -> embB
  gcn4_k<1, 0><<<g4, 256, 0, stream>>>(nullptr, embB, acc, row, col, coef,
                                       noise + 0 * (size_t)NTD, user_emb, item_emb, nullptr);
  // L1: embB -> embA
  gcn4_k<0, 0><<<g4, 256, 0, stream>>>(embB, embA, acc, row, col, coef,
                                       noise + 1 * (size_t)NTD, user_emb, item_emb, nullptr);
  // L2 (LAST, fused mean -> f32 embB + fp16 H0): embA -> embB
  gcn4_k<0, 1><<<g4, 256, 0, stream>>>(embA, embB, acc, row, col, coef,
                                       noise + 2 * (size_t)NTD, user_emb, item_emb, H0);

  // Fused RF layers with fp16 neighbor gathers: (embB,H0) -> (embA,H1) -> out
  rfaccum_k<1><<<g4, 256, 0, stream>>>(embB, H0, embA, H1, row, col);
  rfaccum_k<0><<<g4, 256, 0, stream>>>(embA, H1, out, nullptr, row, col);
}

// Round 14
// 1059.308 us; speedup vs baseline: 1.1745x; 1.0292x over previous
//
#include <hip/hip_runtime.h>
#include <math.h>

// Force numpy-style arithmetic: no FMA contraction, no reassociation.
// RF kernels use explicit fmaf() where fusion is wanted (smooth ops).
#pragma clang fp contract(off)
#pragma clang fp reassociate(off)

#define NU 100000
#define NI 50000
#define NT 150000
#define DD 64
#define NE 2000000
#define NTD (NT * DD)
#define NPART 8
#define PARTW_U (NU / NPART)   // 12500 users per partition
#define PARTW_I (NI / NPART)   // 6250 items per partition
#define NCHUNK 256
#define CHW ((NE + NCHUNK - 1) / NCHUNK)   // 7813 edges per chunk

typedef _Float16 half4 __attribute__((ext_vector_type(4)));

// Block-specialized count: one launch, u-side and i-side blocks run CONCURRENTLY.
// part = blockIdx&7 pins each partition class to one XCD (u-part p and i-part p both
// owned by XCD p; disjoint cnt ranges). side picks which edge array the block reads.
__global__ __launch_bounds__(256) void count_ui_k(const int* __restrict__ eu, const int* __restrict__ ei,
                                                  int* __restrict__ cnt) {
  int part = blockIdx.x & 7;
  int side = (blockIdx.x >> 3) & 1;
  int chunk = blockIdx.x >> 4;
  int e0 = chunk * CHW;
  int e1 = e0 + CHW; if (e1 > NE) e1 = NE;
  if (side == 0) {
    int lo = part * PARTW_U, hi = lo + PARTW_U;
    for (int e = e0 + threadIdx.x; e < e1; e += 256) {
      int u = eu[e];
      if (u >= lo && u < hi) atomicAdd(&cnt[u], 1);
    }
  } else {
    int lo = part * PARTW_I, hi = lo + PARTW_I;
    for (int e = e0 + threadIdx.x; e < e1; e += 256) {
      int it = ei[e];
      if (it >= lo && it < hi) atomicAdd(&cnt[NU + it], 1);
    }
  }
}

__global__ __launch_bounds__(1024) void scanA_k(const int* __restrict__ cnt, int* __restrict__ lexcl,
                                                int* __restrict__ partials, int n) {
  int idx = blockIdx.x * 1024 + threadIdx.x;
  int v = (idx < n) ? cnt[idx] : 0;
  int lane = threadIdx.x & 63;
  int wid = threadIdx.x >> 6;
  int x = v;
#pragma unroll
  for (int off = 1; off < 64; off <<= 1) {
    int y = __shfl_up(x, off, 64);
    if (lane >= off) x += y;
  }
  __shared__ int wtot[16], woff[16];
  if (lane == 63) wtot[wid] = x;
  __syncthreads();
  if (threadIdx.x == 0) {
    int a = 0;
#pragma unroll
    for (int w = 0; w < 16; ++w) { woff[w] = a; a += wtot[w]; }
    partials[blockIdx.x] = a;
  }
  __syncthreads();
  if (idx < n) lexcl[idx] = x - v + woff[wid];
}

__global__ __launch_bounds__(64) void scanB_k(int* __restrict__ partials, int* __restrict__ row, int nchunks) {
  int lane = threadIdx.x;
  int carry = 0;
  for (int base = 0; base < nchunks; base += 64) {
    int idx = base + lane;
    int v = (idx < nchunks) ? partials[idx] : 0;
    int x = v;
#pragma unroll
    for (int off = 1; off < 64; off <<= 1) {
      int y = __shfl_up(x, off, 64);
      if (lane >= off) x += y;
    }
    if (idx < nchunks) partials[idx] = carry + x - v;
    carry += __shfl(x, 63, 64);
  }
  if (lane == 0) row[NT] = carry;
}

__global__ __launch_bounds__(1024) void scanC_k(int* __restrict__ row, int* __restrict__ cursor,
                                                float* __restrict__ coef, const int* __restrict__ partials, int n) {
  int idx = blockIdx.x * 1024 + threadIdx.x;
  if (idx >= n) return;
  int c = cursor[idx];  // raw count
  int fin = row[idx] + partials[blockIdx.x];
  row[idx] = fin;
  cursor[idx] = fin;
  coef[idx] = (float)pow((double)(c > 0 ? c : 1), -0.5);
}

// Block-specialized fill (same decomposition as count_ui_k): u/i sides concurrent,
// per-XCD exclusive ownership of cursor/eid lines preserved.
__global__ __launch_bounds__(256) void fill_ui_k(const int* __restrict__ eu, const int* __restrict__ ei,
                                                 int* __restrict__ cursor, int* __restrict__ eid) {
  int part = blockIdx.x & 7;
  int side = (blockIdx.x >> 3) & 1;
  int chunk = blockIdx.x >> 4;
  int e0 = chunk * CHW;
  int e1 = e0 + CHW; if (e1 > NE) e1 = NE;
  if (side == 0) {
    int lo = part * PARTW_U, hi = lo + PARTW_U;
    for (int e = e0 + threadIdx.x; e < e1; e += 256) {
      int u = eu[e];
      if (u >= lo && u < hi) {
        int p = atomicAdd(&cursor[u], 1);
        eid[p] = e;
      }
    }
  } else {
    int lo = part * PARTW_I, hi = lo + PARTW_I;
    for (int e = e0 + threadIdx.x; e < e1; e += 256) {
      int it = ei[e];
      if (it >= lo && it < hi) {
        int p = atomicAdd(&cursor[NU + it], 1);
        eid[p] = e;
      }
    }
  }
}

// Rank-sort each segment by edge id -> col in exact edge order (deterministic).
__global__ __launch_bounds__(256) void sort_k(const int* __restrict__ row, const int* __restrict__ eid,
                                              const int* __restrict__ eu, const int* __restrict__ ei,
                                              int* __restrict__ col) {
  int wv = (blockIdx.x * blockDim.x + threadIdx.x) >> 6;
  int lane = threadIdx.x & 63;
  if (wv >= NT) return;
  int beg = row[wv], end = row[wv + 1];
  for (int idx = beg + lane; idx < end; idx += 64) {
    int my = eid[idx];
    int r = 0;
    for (int j = beg; j < end; ++j) r += (eid[j] < my);
    col[beg + r] = (wv < NU) ? (NU + ei[my]) : eu[my];
  }
}

// GCN layer: 4 nodes/wave, 16 lanes x float4 dims, depth-4+4 chunked gather pipeline
// (fetch-bound at ~160us/pass: 466 MB L2-miss traffic @ ~3.5 TB/s; depth-6 measured
// neutral). Arithmetic bit-identical: per-dim strict edge-order sum, separate mul/add
// rounding; noise pairwise-sum + fixed tree. FIRST=1: gather straight from ue/ie + init
// acc. LAST=1: fused layer mean -> out (f32) AND h16out (fp16 copy for RF gathers).
template <int FIRST, int LAST>
__global__ __launch_bounds__(256) void gcn4_k(const float* __restrict__ in, float* __restrict__ out,
                                              float* __restrict__ acc,
                                              const int* __restrict__ row, const int* __restrict__ col,
                                              const float* __restrict__ coef, const float* __restrict__ nz_l,
                                              const float* __restrict__ ue, const float* __restrict__ ie,
                                              _Float16* __restrict__ h16out) {
  int wave = (blockIdx.x * blockDim.x + threadIdx.x) >> 6;
  int lane = threadIdx.x & 63;
  int g = lane >> 4, q = lane & 15;
  int node = wave * 4 + g;
  if (node >= NT) return;
  int beg = row[node], end = row[node + 1];
  float cn = coef[node];
  float sx = 0.f, sy = 0.f, sz = 0.f, sw = 0.f;

  const float* gbase;
  if (FIRST) {
    gbase = (node < NU) ? (ie - (size_t)NU * DD) : ue;  // user->item rows, item->user rows
  } else {
    gbase = in;
  }

#define GLD(dv, dc, kk) { int m_ = col[kk]; dc = coef[m_]; dv = *(const float4*)(gbase + (size_t)m_ * DD + q * 4); }
  float4 cv0, cv1, cv2, cv3;
  float cc0, cc1, cc2, cc3;
  int rem = end - beg;
  int k4end = end - (rem & 3);
  int k = beg;
  if (k < k4end) {
    GLD(cv0, cc0, k) GLD(cv1, cc1, k + 1) GLD(cv2, cc2, k + 2) GLD(cv3, cc3, k + 3)
  }
  for (; k < k4end; k += 4) {
    float4 nv0, nv1, nv2, nv3;
    float nc0, nc1, nc2, nc3;
    bool more = (k + 4) < k4end;
    if (more) {
      GLD(nv0, nc0, k + 4) GLD(nv1, nc1, k + 5) GLD(nv2, nc2, k + 6) GLD(nv3, nc3, k + 7)
    }
    {
      float w = cn * cc0;
      sx = sx + (cv0.x * w); sy = sy + (cv0.y * w); sz = sz + (cv0.z * w); sw = sw + (cv0.w * w);
    }
    {
      float w = cn * cc1;
      sx = sx + (cv1.x * w); sy = sy + (cv1.y * w); sz = sz + (cv1.z * w); sw = sw + (cv1.w * w);
    }
    {
      float w = cn * cc2;
      sx = sx + (cv2.x * w); sy = sy + (cv2.y * w); sz = sz + (cv2.z * w); sw = sw + (cv2.w * w);
    }
    {
      float w = cn * cc3;
      sx = sx + (cv3.x * w); sy = sy + (cv3.y * w); sz = sz + (cv3.z * w); sw = sw + (cv3.w * w);
    }
    if (more) {
      cv0 = nv0; cc0 = nc0; cv1 = nv1; cc1 = nc1;
      cv2 = nv2; cc2 = nc2; cv3 = nv3; cc3 = nc3;
    }
  }
  for (; k < end; ++k) {  // tail <= 3
    float4 v; float c;
    GLD(v, c, k)
    float w = cn * c;
    sx = sx + (v.x * w); sy = sy + (v.y * w); sz = sz + (v.z * w); sw = sw + (v.w * w);
  }
#undef GLD

  // Noise norm, bit-identical: r[j] = sum over k of sq[8k+j] (sequential), tree combine.
  float4 nzv = *(const float4*)(nz_l + (size_t)node * DD + q * 4);
  float4 sq;
  sq.x = nzv.x * nzv.x; sq.y = nzv.y * nzv.y;
  sq.z = nzv.z * nzv.z; sq.w = nzv.w * nzv.w;
  float rA0 = 0.f, rA1 = 0.f, rA2 = 0.f, rA3 = 0.f;
  float rB0 = 0.f, rB1 = 0.f, rB2 = 0.f, rB3 = 0.f;
  int base = g * 16;
#pragma unroll
  for (int kk = 0; kk < 8; ++kk) {
    int le = base + 2 * kk, lo = le + 1;
    rA0 = rA0 + __shfl(sq.x, le, 64);
    rA1 = rA1 + __shfl(sq.y, le, 64);
    rA2 = rA2 + __shfl(sq.z, le, 64);
    rA3 = rA3 + __shfl(sq.w, le, 64);
    rB0 = rB0 + __shfl(sq.x, lo, 64);
    rB1 = rB1 + __shfl(sq.y, lo, 64);
    rB2 = rB2 + __shfl(sq.z, lo, 64);
    rB3 = rB3 + __shfl(sq.w, lo, 64);
  }
  float t01 = rA0 + rA1, t23 = rA2 + rA3;
  float t45 = rB0 + rB1, t67 = rB2 + rB3;
  float tot = (t01 + t23) + (t45 + t67);
  float nrm = __fsqrt_rn(tot);
  float den = fmaxf(nrm, 1e-12f);
  float4 o;
  {
    float nn = nzv.x / den;
    float sg = (sx > 0.f) ? 1.f : ((sx < 0.f) ? -1.f : 0.f);
    o.x = sx + ((sg * nn) * 0.2f);
  }
  {
    float nn = nzv.y / den;
    float sg = (sy > 0.f) ? 1.f : ((sy < 0.f) ? -1.f : 0.f);
    o.y = sy + ((sg * nn) * 0.2f);
  }
  {
    float nn = nzv.z / den;
    float sg = (sz > 0.f) ? 1.f : ((sz < 0.f) ? -1.f : 0.f);
    o.z = sz + ((sg * nn) * 0.2f);
  }
  {
    float nn = nzv.w / den;
    float sg = (sw > 0.f) ? 1.f : ((sw < 0.f) ? -1.f : 0.f);
    o.w = sw + ((sg * nn) * 0.2f);
  }
  size_t boff = (size_t)node * DD + q * 4;
  if (FIRST) {
    const float* ownp = (node < NU) ? (ue + (size_t)node * DD) : (ie + (size_t)(node - NU) * DD);
    float4 own = *(const float4*)(ownp + q * 4);
    *(float4*)(out + boff) = o;
    float4 a;
    a.x = own.x + o.x; a.y = own.y + o.y; a.z = own.z + o.z; a.w = own.w + o.w;
    *(float4*)(acc + boff) = a;
  } else {
    float4 a = *(const float4*)(acc + boff);
    if (LAST) {
      float4 mo;
      mo.x = (a.x + o.x) * 0.25f;
      mo.y = (a.y + o.y) * 0.25f;
      mo.z = (a.z + o.z) * 0.25f;
      mo.w = (a.w + o.w) * 0.25f;
      *(float4*)(out + boff) = mo;
      half4 hh;
      hh.x = (_Float16)mo.x; hh.y = (_Float16)mo.y;
      hh.z = (_Float16)mo.z; hh.w = (_Float16)mo.w;
      *(half4*)(h16out + boff) = hh;
    } else {
      *(float4*)(out + boff) = o;
      a.x = a.x + o.x; a.y = a.y + o.y; a.z = a.z + o.z; a.w = a.w + o.w;
      *(float4*)(acc + boff) = a;
    }
  }
}

// Fused Rankformer layer, fp16 neighbor gather (RF smooth; headroom validated r13).
// Own row e and all accumulation stay f32. WRITEH=1 emits fp16 copy for next layer.
template <int WRITEH>
__global__ __launch_bounds__(256) void rfaccum_k(const float* __restrict__ inF,
                                                 const _Float16* __restrict__ inH,
                                                 float* __restrict__ outF,
                                                 _Float16* __restrict__ outH,
                                                 const int* __restrict__ row, const int* __restrict__ col) {
  int wave = (blockIdx.x * blockDim.x + threadIdx.x) >> 6;
  int lane = threadIdx.x & 63;
  int g = lane >> 4, q = lane & 15;
  int node = wave * 4 + g;
  if (node >= NT) return;
  int beg = row[node], end = row[node + 1];
  size_t boff = (size_t)node * DD + q * 4;
  float4 e = *(const float4*)(inF + boff);
  float rx = 0.f, ry = 0.f, rz = 0.f, rw = 0.f, zacc = 0.f;

#define VLD(dv, kk) { dv = *(const half4*)(inH + (size_t)col[kk] * DD + q * 4); }
#define STEP(hv)                                                             \
  {                                                                          \
    float vx = (float)hv.x, vy = (float)hv.y, vz = (float)hv.z, vw = (float)hv.w; \
    float d = fmaf(e.x, vx, fmaf(e.y, vy, fmaf(e.z, vz, e.w * vw)));         \
    d += __shfl_xor(d, 1, 64); d += __shfl_xor(d, 2, 64);                    \
    d += __shfl_xor(d, 4, 64); d += __shfl_xor(d, 8, 64);                    \
    float p = __expf(d);                                                     \
    rx = fmaf(p, vx, rx); ry = fmaf(p, vy, ry);                              \
    rz = fmaf(p, vz, rz); rw = fmaf(p, vw, rw);                              \
    zacc = zacc + p;                                                         \
  }

  half4 cv0, cv1, cv2, cv3;
  int rem = end - beg;
  int k4end = end - (rem & 3);
  int k = beg;
  if (k < k4end) {
    VLD(cv0, k) VLD(cv1, k + 1) VLD(cv2, k + 2) VLD(cv3, k + 3)
  }
  for (; k < k4end; k += 4) {
    half4 nv0, nv1, nv2, nv3;
    bool more = (k + 4) < k4end;
    if (more) {
      VLD(nv0, k + 4) VLD(nv1, k + 5) VLD(nv2, k + 6) VLD(nv3, k + 7)
    }
    STEP(cv0) STEP(cv1) STEP(cv2) STEP(cv3)
    if (more) { cv0 = nv0; cv1 = nv1; cv2 = nv2; cv3 = nv3; }
  }
  for (; k < end; ++k) {
    half4 v;
    VLD(v, k)
    STEP(v)
  }
#undef STEP
#undef VLD

  float zi = 1.f / fmaxf(zacc, 1e-9f);
  float4 o;
  o.x = 0.5f * e.x + 0.5f * (rx * zi);
  o.y = 0.5f * e.y + 0.5f * (ry * zi);
  o.z = 0.5f * e.z + 0.5f * (rz * zi);
  o.w = 0.5f * e.w + 0.5f * (rw * zi);
  *(float4*)(outF + boff) = o;
  if (WRITEH) {
    half4 hh;
    hh.x = (_Float16)o.x; hh.y = (_Float16)o.y;
    hh.z = (_Float16)o.z; hh.w = (_Float16)o.w;
    *(half4*)(outH + boff) = hh;
  }
}

extern "C" void kernel_launch(void* const* d_in, const int* in_sizes, int n_in,
                              void* d_out, int out_size, void* d_ws, size_t ws_size,
                              hipStream_t stream) {
  const float* user_emb = (const float*)d_in[0];
  const float* item_emb = (const float*)d_in[1];
  const float* noise    = (const float*)d_in[2];
  const int*   edge_u   = (const int*)d_in[3];
  const int*   edge_i   = (const int*)d_in[4];
  float* out = (float*)d_out;

  // ws layout (~148 MB)
  float* embA = (float*)d_ws;                      // NTD f32
  float* embB = embA + (size_t)NTD;                // NTD f32
  float* coef = embB + (size_t)NTD;                // NT+16
  int*   row  = (int*)(coef + (NT + 16));          // NT+16
  int*   cursor = row + (NT + 16);                 // NT+16
  int*   partials = cursor + (NT + 16);            // 256
  int*   eidt = partials + 256;                    // 2E
  int*   col  = eidt + 2 * (size_t)NE;             // 2E
  _Float16* H0 = (_Float16*)(col + 2 * (size_t)NE); // NTD fp16
  _Float16* H1 = H0 + (size_t)NTD;                  // NTD fp16

  float* acc = out;  // layer-mean accumulator lives in d_out until the final RF pass

  const int nchunks = (NT + 1023) / 1024;

  hipMemsetAsync(cursor, 0, (size_t)NT * sizeof(int), stream);
  count_ui_k<<<NCHUNK * NPART * 2, 256, 0, stream>>>(edge_u, edge_i, cursor);
  scanA_k<<<nchunks, 1024, 0, stream>>>(cursor, row, partials, NT);
  scanB_k<<<1, 64, 0, stream>>>(partials, row, nchunks);
  scanC_k<<<nchunks, 1024, 0, stream>>>(row, cursor, coef, partials, NT);
  fill_ui_k<<<NCHUNK * NPART * 2, 256, 0, stream>>>(edge_u, edge_i, cursor, eidt);

  const int gwave = (NT * 64 + 255) / 256;   // 64-lane-per-node grid (sort)
  const int g4    = (NT / 4 * 64) / 256;     // 4-node-per-wave grids = 9375

  sort_k<<<gwave, 256, 0, stream>>>(row, eidt, edge_u, edge_i, col);

  // L0 (FIRST, gathers from ue/ie, inits acc): -> embB
  gcn4_k<1, 0><<<g4, 256, 0, stream>>>(nullptr, embB, acc, row, col, coef,
                                       noise + 0 * (size_t)NTD, user_emb, item_emb, nullptr);
  // L1: embB -> embA
  gcn4_k<0, 0><<<g4, 256, 0, stream>>>(embB, embA, acc, row, col, coef,
                                       noise + 1 * (size_t)NTD, user_emb, item_emb, nullptr);
  // L2 (LAST, fused mean -> f32 embB + fp16 H0): embA -> embB
  gcn4_k<0, 1><<<g4, 256, 0, stream>>>(embA, embB, acc, row, col, coef,
                                       noise + 2 * (size_t)NTD, user_emb, item_emb, H0);

  // Fused RF layers with fp16 neighbor gathers: (embB,H0) -> (embA,H1) -> out
  rfaccum_k<1><<<g4, 256, 0, stream>>>(embB, H0, embA, H1, row, col);
  rfaccum_k<0><<<g4, 256, 0, stream>>>(embA, H1, out, nullptr, row, col);
}